// Round 17
// baseline (99.018 us; speedup 1.0000x reference)
//
#include <hip/hip_runtime.h>

#define NXg 4096
#define NYg 4096
#define BROWS 12                // output rows per band
#define ROW0 8                  // band region covers rows [8, 4088)
#define NBANDS 340              // 4080 / 12
#define NPANEL 16               // 4096 / CCOLS
#define CCOLS 256               // core cols per block
#define LCOLS 264               // 4 halo + 256 + 4 halo
#define CPR 66                  // 16B chunks per tile row
#define NCHUNK 3168             // 48 tile rows * 66
#define NJ 13                   // DMA iters: 13*256 = 3328 >= 3168
#define NSLOTF 13312            // 3328 chunk slots * 4 floats (incl. pad)

static constexpr float C = 10.2375f;    // Z*DT/DX = (1/400)*4095 ; DX==DY

typedef float v4f __attribute__((ext_vector_type(4)));   // clang vector: OK for
                                                         // __builtin_nontemporal_store

struct F4  { float v[4];  };
struct F7  { float v[7];  };
struct F10 { float v[10]; };

__device__ __forceinline__ F4 lb4(const float* Lrow, int lc) {
    const float4 b = *(const float4*)(Lrow + lc);
    F4 x; x.v[0] = b.x; x.v[1] = b.y; x.v[2] = b.z; x.v[3] = b.w;
    return x;
}
__device__ __forceinline__ F7 l7(const float* Lrow, int lc) {
    const float4 a = *(const float4*)(Lrow + lc - 4);
    const float4 b = *(const float4*)(Lrow + lc);
    const float4 c = *(const float4*)(Lrow + lc + 4);
    F7 x;
    x.v[0] = a.w; x.v[1] = b.x; x.v[2] = b.y; x.v[3] = b.z;
    x.v[4] = b.w; x.v[5] = c.x; x.v[6] = c.y;
    return x;
}
__device__ __forceinline__ F10 l10(const float* Lrow, int lc) {
    const float4 a = *(const float4*)(Lrow + lc - 4);
    const float4 b = *(const float4*)(Lrow + lc);
    const float4 c = *(const float4*)(Lrow + lc + 4);
    F10 x;
    x.v[0] = a.y; x.v[1] = a.z; x.v[2] = a.w;
    x.v[3] = b.x; x.v[4] = b.y; x.v[5] = b.z; x.v[6] = b.w;
    x.v[7] = c.x; x.v[8] = c.y; x.v[9] = c.z;
    return x;
}
__device__ __forceinline__ F4 mid(const F7& s) {
    F4 x; x.v[0] = s.v[1]; x.v[1] = s.v[2]; x.v[2] = s.v[3]; x.v[3] = s.v[4];
    return x;
}
__device__ __forceinline__ void nt_store4(float* p, float a, float b, float c, float d) {
    v4f v; v.x = a; v.y = b; v.z = c; v.w = d;
    __builtin_nontemporal_store(v, (v4f*)p);
}

// ---------------------------------------------------------------------------
// Fused kernel. blockIdx.y < NBANDS: band path (r15 structure + INTERLEAVED
// tile layout + SPLIT counted-vmcnt drain so compute overlaps DMA arrival).
// blockIdx.y >= NBANDS: edge path (guarded slow path, rows [0,8) / [4088,4096)),
// reusing the same LDS allocation — one dispatch, no serial edge kernel.
//
// Tile slot t (interleaved): t<45 -> triplet k=t/3: {X3[k], X2[k], X1[k]} with
// X3 row k = global i0-3+k, X2/X1 row k = i0-1+k; t=45..47 -> X3 rows 15..17.
// Chunk c (16B) -> slot t=c/66. Resident-prefix after j DMA groups: c < j*256.
//   rows g   (r<=3):  need c < 1848  -> after vmcnt(5)  [j<=7,  c<2048]
//   rows g+4 (r<=7):  need c < 2640  -> after 2nd vmcnt(5) (3 NT stores queued
//                     -> drains 3 more DMAs) [j<=10, c<2816]
//   rows g+8 (r<=11): need all       -> vmcnt(6) (drains last 2 DMAs; 6 store
//                     acks may remain)
// ---------------------------------------------------------------------------
__global__ __launch_bounds__(256) void fused_kernel(
    const float* __restrict__ X1, const float* __restrict__ X2,
    const float* __restrict__ X3, const float* __restrict__ w1,
    float* __restrict__ E, float* __restrict__ Hx, float* __restrict__ Hy)
{
    __shared__ __attribute__((aligned(16))) float B[NSLOTF];

    const int tid  = threadIdx.x;           // 0..255
    const int col0 = blockIdx.x * CCOLS;

    float wv = w1[0];
    float f0 = (wv - 1.0f) / 3.0f;
    float f1 = -wv;
    float f2 = wv;
    float f3 = (1.0f - wv) / 3.0f;
    // materialize before staging: keeps the compiler's w1-load wait here,
    // not as a conservative vmcnt(0) inside batch 1.
    asm volatile("" : "+v"(f0), "+v"(f1), "+v"(f2), "+v"(f3));

    // ======================= edge path =======================
    if (blockIdx.y >= NBANDS) {
        const int row0 = (blockIdx.y == NBANDS) ? 0 : (NXg - 8);

        for (int cidx = tid; cidx < 12 * LCOLS; cidx += 256) {
            const int r  = cidx / LCOLS;
            const int cc = cidx - r * LCOLS;
            const int gr = row0 - 2 + r;
            const int gc = col0 - 4 + cc;
            float e = 0.0f;
            if (gr >= 0 && gr < NXg && gc >= 0 && gc < NYg) {
                const size_t idx = (size_t)gr * NYg + gc;
                const float x1 = X1[idx];
                if (gr == 0 || gr == NXg - 1 || gc == 0 || gc == NYg - 1) {
                    e = x1;
                } else {
                    float e1 = x1 + C * (X3[idx] - X3[idx - NYg])
                                  - C * (X2[idx] - X2[idx - 1]);
                    if (gr >= 2 && gr <= NXg - 3 && gc >= 2 && gc <= NYg - 3) {
                        e1 += C * (f0 * X3[idx - 2 * NYg] + f1 * X3[idx - NYg]
                                 + f2 * X3[idx] + f3 * X3[idx + NYg])
                            - C * (f0 * X2[idx - 2] + f1 * X2[idx - 1]
                                 + f2 * X2[idx] + f3 * X2[idx + 1]);
                    }
                    e = e1;
                }
            }
            B[r * LCOLS + cc] = e;
        }
        __syncthreads();

        for (int cidx = tid; cidx < 8 * CCOLS; cidx += 256) {
            const int hr  = cidx >> 8;
            const int tc  = cidx & (CCOLS - 1);
            const int gr  = row0 + hr;
            const int gcc = col0 + tc;
            const size_t idx = (size_t)gr * NYg + gcc;
            const int lr  = hr + 2;
            const int lc2 = tc + 4;

            const float ec = B[lr * LCOLS + lc2];
            E[idx] = ec;

            const float x1 = X1[idx];

            float hx = X2[idx];
            if (gr >= 1 && gr <= NXg - 2 && gcc <= NYg - 2)
                hx -= C * (X1[idx + 1] - x1);
            if (gr >= 2 && gr <= NXg - 3 && gcc >= 1 && gcc <= NYg - 3) {
                hx -= C * (f0 * B[lr * LCOLS + lc2 - 1] + f1 * ec
                         + f2 * B[lr * LCOLS + lc2 + 1] + f3 * B[lr * LCOLS + lc2 + 2]);
            }
            Hx[idx] = hx;

            float hy = X3[idx];
            if (gr <= NXg - 2 && gcc >= 1 && gcc <= NYg - 2)
                hy += C * (X1[idx + NYg] - x1);
            if (gr >= 1 && gr <= NXg - 3 && gcc >= 2 && gcc <= NYg - 3) {
                hy += C * (f0 * B[(lr - 1) * LCOLS + lc2] + f1 * ec
                         + f2 * B[(lr + 1) * LCOLS + lc2] + f3 * B[(lr + 2) * LCOLS + lc2]);
            }
            Hy[idx] = hy;
        }
        return;
    }

    // ======================= band path =======================
    const int i0 = ROW0 + blockIdx.y * BROWS;

    const int cq = tid & 63;                // col quad 0..63 (full wave = one row)
    const int g  = tid >> 6;                // wave id 0..3; owns rows g, g+4, g+8
    const int lc = 4 + 4 * cq;
    const bool gL = (blockIdx.x == 0) && (cq == 0);
    const bool gR = (blockIdx.x == NPANEL - 1) && (cq == 63);

    // ---- stage: 13 DMAs per thread, interleaved tile layout ----
    {
        #pragma unroll
        for (int j = 0; j < NJ; ++j) {
            const int c    = j * 256 + tid;
            const int cc2  = (c < NCHUNK) ? c : (NCHUNK - 1);
            const int t    = cc2 / CPR;
            const int col4 = cc2 - t * CPR;
            const float* base;
            int grow;
            if (t < 45) {
                const int k = t / 3;
                const int m = t - 3 * k;
                base = (m == 0) ? X3 : ((m == 1) ? X2 : X1);
                grow = i0 + ((m == 0) ? (k - 3) : (k - 1));
            } else {
                base = X3;
                grow = i0 + (t - 33);       // t=45..47 -> i0+12..i0+14
            }
            const float* gp = base + (size_t)grow * NYg + (col0 - 4) + col4 * 4;
            float* lp = B + j * 1024 + (tid >> 6) * 256;   // wave-uniform base
            __builtin_amdgcn_global_load_lds(
                (const __attribute__((address_space(1))) void*)gp,
                (__attribute__((address_space(3))) void*)lp, 16, 0, 0);
        }
    }

    // interleaved row pointers
    auto T3row = [&](int k) { return B + ((k <= 14) ? 3 * k : 30 + k) * LCOLS; };
    auto T2row = [&](int k) { return B + (3 * k + 1) * LCOLS; };
    auto T1row = [&](int k) { return B + (3 * k + 2) * LCOLS; };

    auto eRow4 = [&](const F4& a, const F4& b, const F4& cc, const F4& d,
                     const F10& x2r, const F4& x1r) -> F4 {
        F4 e;
        #pragma unroll
        for (int q = 0; q < 4; ++q) {
            const float e1 = x1r.v[q] + C * (cc.v[q] - b.v[q])
                                      - C * (x2r.v[q + 3] - x2r.v[q + 2]);
            e.v[q] = e1
                + C * (f0 * a.v[q] + f1 * b.v[q] + f2 * cc.v[q] + f3 * d.v[q])
                - C * (f0 * x2r.v[q + 1] + f1 * x2r.v[q + 2]
                     + f2 * x2r.v[q + 3] + f3 * x2r.v[q + 4]);
        }
        if (gL) {
            e.v[0] = x1r.v[0];
            e.v[1] = x1r.v[1] + C * (cc.v[1] - b.v[1])
                              - C * (x2r.v[4] - x2r.v[3]);
        }
        if (gR) {
            e.v[3] = x1r.v[3];
            e.v[2] = x1r.v[2] + C * (cc.v[2] - b.v[2])
                              - C * (x2r.v[5] - x2r.v[4]);
        }
        return e;
    };

    auto computeRow = [&](int r) {
        const int i = i0 + r;

        const F4  x3m3 = lb4(T3row(r    ), lc);
        const F7  x3m2 = l7 (T3row(r + 1), lc);
        const F7  x3m1 = l7 (T3row(r + 2), lc);
        const F7  x3i  = l7 (T3row(r + 3), lc);
        const F7  x3p1 = l7 (T3row(r + 4), lc);
        const F4  x3p2 = lb4(T3row(r + 5), lc);
        const F4  x3p3 = lb4(T3row(r + 6), lc);

        const F10 x2m1 = l10(T2row(r    ), lc);
        const F10 x2i  = l10(T2row(r + 1), lc);
        const F10 x2p1 = l10(T2row(r + 2), lc);
        const F10 x2p2 = l10(T2row(r + 3), lc);

        const F4  x1m1 = lb4(T1row(r    ), lc);
        const F7  x1i  = l7 (T1row(r + 1), lc);
        const F4  x1p1 = lb4(T1row(r + 2), lc);
        const F4  x1p2 = lb4(T1row(r + 3), lc);

        // E row i, 7-wide
        F7 e7;
        #pragma unroll
        for (int m = 0; m < 7; ++m) {
            const float e1 = x1i.v[m] + C * (x3i.v[m] - x3m1.v[m])
                                      - C * (x2i.v[m + 2] - x2i.v[m + 1]);
            e7.v[m] = e1
                + C * (f0 * x3m2.v[m] + f1 * x3m1.v[m] + f2 * x3i.v[m] + f3 * x3p1.v[m])
                - C * (f0 * x2i.v[m] + f1 * x2i.v[m + 1] + f2 * x2i.v[m + 2] + f3 * x2i.v[m + 3]);
        }
        if (gL) {
            e7.v[1] = x1i.v[1];
            e7.v[2] = x1i.v[2] + C * (x3i.v[2] - x3m1.v[2])
                               - C * (x2i.v[4] - x2i.v[3]);
        }
        if (gR) {
            e7.v[4] = x1i.v[4];
            e7.v[3] = x1i.v[3] + C * (x3i.v[3] - x3m1.v[3])
                               - C * (x2i.v[5] - x2i.v[4]);
        }

        const F4 em1 = eRow4(x3m3,      mid(x3m2), mid(x3m1), mid(x3i), x2m1, x1m1);
        const F4 ep1 = eRow4(mid(x3m1), mid(x3i),  mid(x3p1), x3p2,     x2p1, x1p1);
        const F4 ep2 = eRow4(mid(x3i),  mid(x3p1), x3p2,      x3p3,     x2p2, x1p2);

        float hx[4], hy[4];
        #pragma unroll
        for (int q = 0; q < 4; ++q) {
            hx[q] = x2i.v[q + 3] - C * (x1i.v[q + 2] - x1i.v[q + 1])
                  - C * (f0 * e7.v[q] + f1 * e7.v[q + 1]
                       + f2 * e7.v[q + 2] + f3 * e7.v[q + 3]);
            hy[q] = x3i.v[q + 1] + C * (x1p1.v[q] - x1i.v[q + 1])
                  + C * (f0 * em1.v[q] + f1 * e7.v[q + 1]
                       + f2 * ep1.v[q] + f3 * ep2.v[q]);
        }
        if (gL) {
            hx[0] = x2i.v[3] - C * (x1i.v[2] - x1i.v[1]);
            hy[0] = x3i.v[1];
            hy[1] = x3i.v[2] + C * (x1p1.v[1] - x1i.v[2]);
        }
        if (gR) {
            hx[3] = x2i.v[6];
            hy[3] = x3i.v[4];
            hx[2] = x2i.v[5] - C * (x1i.v[4] - x1i.v[3]);
            hy[2] = x3i.v[3] + C * (x1p1.v[2] - x1i.v[3]);
        }

        const size_t idx = (size_t)i * NYg + col0 + 4 * cq;
        nt_store4(E  + idx, e7.v[1], e7.v[2], e7.v[3], e7.v[4]);
        nt_store4(Hx + idx, hx[0], hx[1], hx[2], hx[3]);
        nt_store4(Hy + idx, hy[0], hy[1], hy[2], hy[3]);
    };

    // ---- split drain: compute overlaps DMA arrival ----
    asm volatile("s_waitcnt vmcnt(5)" ::: "memory");   // j<=7 resident (c<2048)
    __builtin_amdgcn_s_barrier();
    computeRow(g);                                     // needs c<1848; +3 stores
    asm volatile("s_waitcnt vmcnt(5)" ::: "memory");   // drains 3 more DMAs (j<=10)
    __builtin_amdgcn_s_barrier();
    computeRow(g + 4);                                 // needs c<2640; +3 stores
    asm volatile("s_waitcnt vmcnt(6)" ::: "memory");   // drains last 2 DMAs
    __builtin_amdgcn_s_barrier();
    computeRow(g + 8);                                 // needs all chunks
}

extern "C" void kernel_launch(void* const* d_in, const int* in_sizes, int n_in,
                              void* d_out, int out_size, void* d_ws, size_t ws_size,
                              hipStream_t stream) {
    const float* X1 = (const float*)d_in[0];
    const float* X2 = (const float*)d_in[1];
    const float* X3 = (const float*)d_in[2];
    const float* w1 = (const float*)d_in[3];

    float* E  = (float*)d_out;
    float* Hx = (float*)d_out + (size_t)NXg * NYg;
    float* Hy = (float*)d_out + 2 * (size_t)NXg * NYg;

    fused_kernel<<<dim3(NPANEL, NBANDS + 2), 256, 0, stream>>>(
        X1, X2, X3, w1, E, Hx, Hy);
}